// Round 8
// baseline (595.682 us; speedup 1.0000x reference)
//
#include <hip/hip_runtime.h>

#define NN 40000
#define NE 640000
#define HID 128
#define SCAN_BLK ((NN + 255) / 256)   // 157

typedef __attribute__((ext_vector_type(8)))  short short8;
typedef __attribute__((ext_vector_type(16))) float floatx16;
typedef unsigned int uint;

__device__ __forceinline__ short f2bf(float f) {
    union { float f; unsigned u; } c; c.f = f;
    unsigned u = c.u;
    unsigned r = (u + 0x7FFF + ((u >> 16) & 1)) >> 16;   // RNE
    return (short)r;
}
__device__ __forceinline__ float bf2f(short h) {
    union { unsigned u; float f; } c;
    c.u = ((unsigned)(unsigned short)h) << 16;
    return c.f;
}
__device__ __forceinline__ float asf(uint u) {
    union { uint u; float f; } c; c.u = u; return c.f;
}
// Packed split-bf16: u32 = (hi_bf16 << 16) | lo_bf16; hi+lo ~ x to ~2^-17 rel.
__device__ __forceinline__ uint packsplit(float f) {
    short h = f2bf(f);
    short l = f2bf(f - bf2f(h));
    return ((uint)(unsigned short)h << 16) | (uint)(unsigned short)l;
}
__device__ __forceinline__ float unpackf(uint u) {
    return asf(u & 0xFFFF0000u) + asf(u << 16);
}
// 8 packed uints (two uint4) -> hi-plane short8 + lo-plane short8
__device__ __forceinline__ void unpack8(uint4 a, uint4 b, short8* h, short8* l) {
    short8 H, L;
    H[0] = (short)(a.x >> 16); L[0] = (short)a.x;
    H[1] = (short)(a.y >> 16); L[1] = (short)a.y;
    H[2] = (short)(a.z >> 16); L[2] = (short)a.z;
    H[3] = (short)(a.w >> 16); L[3] = (short)a.w;
    H[4] = (short)(b.x >> 16); L[4] = (short)b.x;
    H[5] = (short)(b.y >> 16); L[5] = (short)b.y;
    H[6] = (short)(b.z >> 16); L[6] = (short)b.z;
    H[7] = (short)(b.w >> 16); L[7] = (short)b.w;
    *h = H; *l = L;
}

// ---------------- split-bf16 MFMA linear, LDS-free direct fragment loads ----
// out[N][128] = relu?( X · W^T + b ). X = PHASES blocks of 128 packed cols
// (X0, X1), row stride 128; W packed, [128][PHASES*128] row-major.
// acc += xh*wh + xl*wh + xh*wl (fp32 accum) -> fp32-grade result.
// Tile: 64 rows x 128 cols per block (625 blocks). 4 waves: wave&1 -> row
// slab (32), wave>>1 -> col pair (64). Each lane loads its MFMA fragments
// (8 k-consecutive elems) directly from global; X rows are block-exclusive,
// W stays L2-hot. One barrier before the epilogue makes in-place out==X0
// safe (both col-pair waves finish reading a row slab before it's written).
template<int PHASES, bool RELU>
__global__ __launch_bounds__(256, 4) void mfma_lin_kernel(
    const uint* __restrict__ X0, const uint* __restrict__ X1,
    const uint* __restrict__ W, const float* __restrict__ b,
    uint* __restrict__ out)
{
    const int t    = threadIdx.x;
    const int wave = t >> 6;
    const int lane = t & 63;
    const int m31  = lane & 31;
    const int half = lane >> 5;
    const int slab = wave & 1;               // row slab within 64-row tile
    const int cp   = wave >> 1;              // col pair (64 cols each)
    const int r0   = blockIdx.x * 64;
    const int WS   = PHASES * 128;
    const int grow = r0 + slab * 32 + m31;   // the X row this lane loads
    const bool rowok = grow < NN;

    floatx16 acc[2];
    #pragma unroll
    for (int ct = 0; ct < 2; ++ct)
        #pragma unroll
        for (int i = 0; i < 16; ++i) acc[ct][i] = 0.f;

    for (int s = 0; s < 2 * PHASES; ++s) {   // k-stages of 64
        const int p   = s >> 1;
        const int xc0 = (s & 1) * 64;        // col offset within X row
        const int wc0 = p * 128 + xc0;       // col offset within W row
        const uint* Xp = (PHASES == 2 && p == 1) ? X1 : X0;
        const uint* xr = Xp + (size_t)grow * 128 + xc0 + half * 8;

        #pragma unroll 2
        for (int kc = 0; kc < 4; ++kc) {     // 4 x K16
            uint4 a0 = make_uint4(0,0,0,0), a1 = make_uint4(0,0,0,0);
            if (rowok) {
                a0 = *(const uint4*)(xr + kc * 16);
                a1 = *(const uint4*)(xr + kc * 16 + 4);
            }
            short8 ah, al;
            unpack8(a0, a1, &ah, &al);
            #pragma unroll
            for (int ct = 0; ct < 2; ++ct) {
                const int col = cp * 64 + ct * 32 + m31;
                const uint* wr = W + (size_t)col * WS + wc0 + half * 8 + kc * 16;
                uint4 w0 = *(const uint4*)(wr);
                uint4 w1 = *(const uint4*)(wr + 4);
                short8 bh, bl;
                unpack8(w0, w1, &bh, &bl);
                acc[ct] = __builtin_amdgcn_mfma_f32_32x32x16_bf16(ah, bh, acc[ct], 0, 0, 0);
                acc[ct] = __builtin_amdgcn_mfma_f32_32x32x16_bf16(al, bh, acc[ct], 0, 0, 0);
                acc[ct] = __builtin_amdgcn_mfma_f32_32x32x16_bf16(ah, bl, acc[ct], 0, 0, 0);
            }
        }
    }

    __syncthreads();   // all X reads of this block done before in-place store

    // epilogue: bias + relu + pack + store.
    // C/D: col=lane&31, row=(reg&3)+8*(reg>>2)+4*half
    #pragma unroll
    for (int ct = 0; ct < 2; ++ct) {
        const int col = cp * 64 + ct * 32 + m31;
        const float bias = b[col];
        #pragma unroll
        for (int reg = 0; reg < 16; ++reg) {
            int row = (reg & 3) + 8 * (reg >> 2) + 4 * half;
            int gr  = r0 + slab * 32 + row;
            if (gr < NN) {
                float v = acc[ct][reg] + bias;
                if (RELU) v = fmaxf(v, 0.f);
                out[(size_t)gr * HID + col] = packsplit(v);
            }
        }
    }
}

// ---------------- fp32 linear for K=11 (first embed only), packs output ----
template<int K, bool RELU>
__global__ __launch_bounds__(128) void lin_kernel(
    const float* __restrict__ X, const float* __restrict__ W,
    const float* __restrict__ b, uint* __restrict__ out, int n_rows)
{
    constexpr int ROWS = 8;
    __shared__ float xs[ROWS * K];
    const int m  = threadIdx.x;
    const int r0 = blockIdx.x * ROWS;
    for (int i = threadIdx.x; i < ROWS * K; i += 128) {
        int r = i / K, k = i - r * K;
        int row = r0 + r;
        xs[i] = (row < n_rows) ? X[(size_t)row * K + k] : 0.f;
    }
    __syncthreads();
    float acc[ROWS] = {};
    const float* Wm = W + (size_t)m * K;
    for (int k = 0; k < K; ++k) {
        float w = Wm[k];
        #pragma unroll
        for (int r = 0; r < ROWS; ++r) acc[r] += xs[r * K + k] * w;
    }
    const float bias = b[m];
    #pragma unroll
    for (int r = 0; r < ROWS; ++r) {
        int row = r0 + r;
        if (row < n_rows) {
            float v = acc[r] + bias;
            if (RELU) v = fmaxf(v, 0.f);
            out[(size_t)row * HID + m] = packsplit(v);
        }
    }
}

// ---------------- weight pre-split (once per launch, 131072 elems) ----------
__global__ __launch_bounds__(256) void wprep_kernel(
    const float* __restrict__ w0, const float* __restrict__ w1,
    const float* __restrict__ w2, const float* __restrict__ w3,
    const float* __restrict__ w4, const float* __restrict__ w5,
    uint* __restrict__ wp)
{
    int i = blockIdx.x * 256 + threadIdx.x;
    if (i >= 131072) return;
    const float* src; int off;
    if      (i < 16384)  { src = w0; off = 0; }
    else if (i < 49152)  { src = w1; off = 16384; }
    else if (i < 65536)  { src = w2; off = 49152; }
    else if (i < 81920)  { src = w3; off = 65536; }
    else if (i < 114688) { src = w4; off = 81920; }
    else                 { src = w5; off = 114688; }
    wp[i] = packsplit(src[i - off]);
}

// ---------------- CSR build (by dst) ----------------
__global__ __launch_bounds__(256) void hist_kernel(
    const int* __restrict__ dst, int* __restrict__ cnt)
{
    int e = blockIdx.x * 256 + threadIdx.x;
    if (e < NE) atomicAdd(&cnt[dst[e]], 1);
}

__global__ __launch_bounds__(256) void scan1_kernel(
    const int* __restrict__ cnt, int* __restrict__ row_ptr,
    int* __restrict__ partials)
{
    __shared__ int s[256];
    const int t = threadIdx.x;
    const int i = blockIdx.x * 256 + t;
    int v = (i < NN) ? cnt[i] : 0;
    s[t] = v;
    __syncthreads();
    #pragma unroll
    for (int off = 1; off < 256; off <<= 1) {
        int x = (t >= off) ? s[t - off] : 0;
        __syncthreads();
        s[t] += x;
        __syncthreads();
    }
    if (i < NN) row_ptr[i] = s[t] - v;
    if (t == 255) partials[blockIdx.x] = s[255];
}

__global__ __launch_bounds__(256) void scan2_kernel(
    int* __restrict__ partials, int* __restrict__ row_ptr)
{
    __shared__ int s[256];
    const int t = threadIdx.x;
    int v = (t < SCAN_BLK) ? partials[t] : 0;
    s[t] = v;
    __syncthreads();
    #pragma unroll
    for (int off = 1; off < 256; off <<= 1) {
        int x = (t >= off) ? s[t - off] : 0;
        __syncthreads();
        s[t] += x;
        __syncthreads();
    }
    if (t < SCAN_BLK) partials[t] = s[t] - v;
    if (t == 255) row_ptr[NN] = s[255];
}

__global__ __launch_bounds__(256) void scan3_kernel(
    int* __restrict__ row_ptr, const int* __restrict__ partials)
{
    const int i = blockIdx.x * 256 + threadIdx.x;
    if (i < NN) row_ptr[i] += partials[blockIdx.x];
}

__global__ __launch_bounds__(256) void fill_kernel(
    const int* __restrict__ src, const int* __restrict__ dst,
    const int* __restrict__ row_ptr, int* __restrict__ pos,
    int* __restrict__ esrc)
{
    int e = blockIdx.x * 256 + threadIdx.x;
    if (e >= NE) return;
    int d = dst[e];
    int p = row_ptr[d] + atomicAdd(&pos[d], 1);
    esrc[p] = src[e];
}

// ---------------- Gather aggregation (packed in/out, unroll x2) -------------
__global__ __launch_bounds__(256) void gather_agg_kernel(
    const uint* __restrict__ h, const int* __restrict__ row_ptr,
    const int* __restrict__ esrc, uint* __restrict__ agg)
{
    int t = blockIdx.x * 256 + threadIdx.x;
    int node = t >> 5;
    int c4   = t & 31;
    if (node >= NN) return;
    const int lo = row_ptr[node], hi = row_ptr[node + 1];
    float4 aH = make_float4(0,0,0,0), aL = make_float4(0,0,0,0);
    float4 bH = make_float4(0,0,0,0), bL = make_float4(0,0,0,0);
    int e = lo;
    for (; e + 2 <= hi; e += 2) {
        int s0 = esrc[e], s1 = esrc[e + 1];
        uint4 u0 = *(const uint4*)(h + (size_t)s0 * HID + c4 * 4);
        uint4 u1 = *(const uint4*)(h + (size_t)s1 * HID + c4 * 4);
        aH.x += asf(u0.x & 0xFFFF0000u); aL.x += asf(u0.x << 16);
        aH.y += asf(u0.y & 0xFFFF0000u); aL.y += asf(u0.y << 16);
        aH.z += asf(u0.z & 0xFFFF0000u); aL.z += asf(u0.z << 16);
        aH.w += asf(u0.w & 0xFFFF0000u); aL.w += asf(u0.w << 16);
        bH.x += asf(u1.x & 0xFFFF0000u); bL.x += asf(u1.x << 16);
        bH.y += asf(u1.y & 0xFFFF0000u); bL.y += asf(u1.y << 16);
        bH.z += asf(u1.z & 0xFFFF0000u); bL.z += asf(u1.z << 16);
        bH.w += asf(u1.w & 0xFFFF0000u); bL.w += asf(u1.w << 16);
    }
    if (e < hi) {
        int s0 = esrc[e];
        uint4 u0 = *(const uint4*)(h + (size_t)s0 * HID + c4 * 4);
        aH.x += asf(u0.x & 0xFFFF0000u); aL.x += asf(u0.x << 16);
        aH.y += asf(u0.y & 0xFFFF0000u); aL.y += asf(u0.y << 16);
        aH.z += asf(u0.z & 0xFFFF0000u); aL.z += asf(u0.z << 16);
        aH.w += asf(u0.w & 0xFFFF0000u); aL.w += asf(u0.w << 16);
    }
    uint4 o;
    o.x = packsplit((aH.x + bH.x) + (aL.x + bL.x));
    o.y = packsplit((aH.y + bH.y) + (aL.y + bL.y));
    o.z = packsplit((aH.z + bH.z) + (aL.z + bL.z));
    o.w = packsplit((aH.w + bH.w) + (aL.w + bL.w));
    *(uint4*)(agg + (size_t)node * HID + c4 * 4) = o;
}

// ---------------- Head ----------------
__global__ __launch_bounds__(256) void head_out_kernel(
    const uint* __restrict__ h, const float* __restrict__ w,
    const float* __restrict__ b, float* __restrict__ out)
{
    long long t = (long long)blockIdx.x * blockDim.x + threadIdx.x;
    int node = (int)(t >> 6);
    int lane = threadIdx.x & 63;
    if (node >= NN) return;
    const uint* hr = h + (size_t)node * HID;
    float a = unpackf(hr[lane]) * w[lane] + unpackf(hr[64 + lane]) * w[64 + lane];
    #pragma unroll
    for (int off = 32; off > 0; off >>= 1) a += __shfl_down(a, off);
    if (lane == 0) out[node] = a + b[0];
}

extern "C" void kernel_launch(void* const* d_in, const int* in_sizes, int n_in,
                              void* d_out, int out_size, void* d_ws, size_t ws_size,
                              hipStream_t stream)
{
    const float* x     = (const float*)d_in[0];
    const int*   eidx  = (const int*)d_in[1];
    const float* c0_w1 = (const float*)d_in[2],  *c0_b1 = (const float*)d_in[3];
    const float* c0_w2 = (const float*)d_in[4],  *c0_b2 = (const float*)d_in[5];
    const float* c0_w3 = (const float*)d_in[6],  *c0_b3 = (const float*)d_in[7];
    const float* c1_w1 = (const float*)d_in[8],  *c1_b1 = (const float*)d_in[9];
    const float* c1_w2 = (const float*)d_in[10], *c1_b2 = (const float*)d_in[11];
    const float* c1_w3 = (const float*)d_in[12], *c1_b3 = (const float*)d_in[13];
    const float* f_w1  = (const float*)d_in[14], *f_b1  = (const float*)d_in[15];
    const float* f_w2  = (const float*)d_in[16], *f_b2  = (const float*)d_in[17];
    const int* src = eidx;
    const int* dst = eidx + NE;
    float* out = (float*)d_out;

    const size_t BUF = (size_t)NN * HID;
    uint* bA = (uint*)d_ws;
    uint* bB = bA + BUF;
    uint* bC = bB + BUF;
    int* row_ptr  = (int*)(bC + BUF);        // NN+1
    int* cnt      = row_ptr + (NN + 1);      // NN (reused as fill cursor)
    int* esrc     = cnt + NN;                // NE
    int* partials = esrc + NE;               // SCAN_BLK
    uint* wp      = (uint*)(partials + SCAN_BLK);  // 131072 packed weights

    // packed-weight offsets in wp
    uint* p_c0w2 = wp + 0;
    uint* p_c0w3 = wp + 16384;
    uint* p_c1w1 = wp + 49152;
    uint* p_c1w2 = wp + 65536;
    uint* p_c1w3 = wp + 81920;
    uint* p_fw1  = wp + 114688;

    const int nb8  = (NN + 7) / 8;            // 5000 (K=11 lin)
    const int nbm  = (NN + 63) / 64;          // 625 (mfma lin)
    const int eb   = (NE + 255) / 256;        // 2500
    const int gb   = (NN * 32 + 255) / 256;   // 5000
    const int hb   = (NN * 64 + 255) / 256;   // 10000

    // ---- weight prep + CSR build ----
    wprep_kernel<<<512, 256, 0, stream>>>(c0_w2, c0_w3, c1_w1, c1_w2, c1_w3, f_w1, wp);
    (void)hipMemsetAsync(cnt, 0, NN * sizeof(int), stream);
    hist_kernel<<<eb, 256, 0, stream>>>(dst, cnt);
    scan1_kernel<<<SCAN_BLK, 256, 0, stream>>>(cnt, row_ptr, partials);
    scan2_kernel<<<1, 256, 0, stream>>>(partials, row_ptr);
    scan3_kernel<<<SCAN_BLK, 256, 0, stream>>>(row_ptr, partials);
    (void)hipMemsetAsync(cnt, 0, NN * sizeof(int), stream);
    fill_kernel<<<eb, 256, 0, stream>>>(src, dst, row_ptr, cnt, esrc);

    // ---- conv0 ----
    lin_kernel<11, true><<<nb8, 128, 0, stream>>>(x, c0_w1, c0_b1, bA, NN);
    gather_agg_kernel<<<gb, 256, 0, stream>>>(bA, row_ptr, esrc, bB);
    mfma_lin_kernel<1, true><<<nbm, 256, 0, stream>>>(bB, nullptr, p_c0w2, c0_b2, bB);
    gather_agg_kernel<<<gb, 256, 0, stream>>>(bB, row_ptr, esrc, bC);
    mfma_lin_kernel<1, true><<<nbm, 256, 0, stream>>>(bC, nullptr, p_c0w2, c0_b2, bC);
    mfma_lin_kernel<2, false><<<nbm, 256, 0, stream>>>(bB, bC, p_c0w3, c0_b3, bA);

    // ---- conv1 ----
    mfma_lin_kernel<1, true><<<nbm, 256, 0, stream>>>(bA, nullptr, p_c1w1, c1_b1, bA);
    gather_agg_kernel<<<gb, 256, 0, stream>>>(bA, row_ptr, esrc, bB);
    mfma_lin_kernel<1, true><<<nbm, 256, 0, stream>>>(bB, nullptr, p_c1w2, c1_b2, bB);
    gather_agg_kernel<<<gb, 256, 0, stream>>>(bB, row_ptr, esrc, bC);
    mfma_lin_kernel<1, true><<<nbm, 256, 0, stream>>>(bC, nullptr, p_c1w2, c1_b2, bC);
    mfma_lin_kernel<2, false><<<nbm, 256, 0, stream>>>(bB, bC, p_c1w3, c1_b3, bA);

    // ---- head ----
    mfma_lin_kernel<1, true><<<nbm, 256, 0, stream>>>(bA, nullptr, p_fw1, f_b1, bA);
    head_out_kernel<<<hb, 256, 0, stream>>>(bA, f_w2, f_b2, out);
}